// Round 4
// baseline (505.626 us; speedup 1.0000x reference)
//
#include <hip/hip_runtime.h>
#include <hip/hip_bf16.h>
#include <math.h>

typedef __attribute__((ext_vector_type(8))) short bf16x8;   // 8 bf16 in 4 VGPRs
typedef __attribute__((ext_vector_type(4))) float f32x4;    // MFMA C/D frag
typedef unsigned short ushort_t;

__device__ __forceinline__ ushort_t f2bf(float f) {
    union { float f; unsigned u; } v; v.f = f;
    unsigned r = v.u + 0x7FFF + ((v.u >> 16) & 1);   // RNE
    return (ushort_t)(r >> 16);
}

// pack two f32 -> 2 bf16 (round-half-up): 2 adds + 1 v_perm; a in low half
__device__ __forceinline__ unsigned pack2bf(float a, float b) {
    union { float f; unsigned u; } x, y; x.f = a; y.f = b;
    return __builtin_amdgcn_perm(y.u + 0x8000u, x.u + 0x8000u, 0x07060302u);
}

// async 16B global -> LDS (wave-uniform LDS base; lane data lands at base+lane*16)
__device__ __forceinline__ void gl2lds(const void* g, void* l) {
    __builtin_amdgcn_global_load_lds(
        (const __attribute__((address_space(1))) void*)g,
        (__attribute__((address_space(3))) void*)l, 16, 0, 0);
}

// fast GELU (tanh form via sigmoid): max |err| vs erf-GELU ~1e-3
__device__ __forceinline__ float fast_gelu(float tt) {
    float t2 = tt * tt;
    float arg = tt * fmaf(0.07135481283f, t2, 1.595769122f);
    float e = __builtin_amdgcn_exp2f(arg * -1.442695041f);
    return tt * __builtin_amdgcn_rcpf(1.0f + e);
}

// ---------------------------------------------------------------------------
// Merged transpose+cast for all 4 weights (one launch).
// out[c*R + r] = bf16(in[r*Cc + c]); wqkv rows n<1024 scaled by qscale.
// grid: 3072 (wqkv 96x32) + 1024 (wproj 32x32) + 4096 (w1 128x32) + 4096 (w2 32x128)
// ---------------------------------------------------------------------------
__global__ __launch_bounds__(256)
void tcast_all(const float* __restrict__ wqkv, const float* __restrict__ wproj,
               const float* __restrict__ w1, const float* __restrict__ w2,
               ushort_t* __restrict__ wqkvT, ushort_t* __restrict__ wprojT,
               ushort_t* __restrict__ w1T, ushort_t* __restrict__ w2T,
               float qscale) {
    __shared__ float tile[32][33];
    int id = blockIdx.x;
    const float* in; ushort_t* out; int R, Cc, gx, scale_n;
    if (id < 3072)      { in = wqkv;  out = wqkvT;  R = 1024; Cc = 3072; gx = 96;  scale_n = 1024; }
    else if (id < 4096) { id -= 3072; in = wproj; out = wprojT; R = 1024; Cc = 1024; gx = 32; scale_n = 0; }
    else if (id < 8192) { id -= 4096; in = w1;    out = w1T;    R = 1024; Cc = 4096; gx = 128; scale_n = 0; }
    else                { id -= 8192; in = w2;    out = w2T;    R = 4096; Cc = 1024; gx = 32; scale_n = 0; }
    int bc = (id % gx) * 32, br = (id / gx) * 32;
    int tx = threadIdx.x, ty = threadIdx.y;
    #pragma unroll
    for (int i = 0; i < 32; i += 8)
        tile[ty + i][tx] = in[(size_t)(br + ty + i) * Cc + bc + tx];
    __syncthreads();
    #pragma unroll
    for (int i = 0; i < 32; i += 8) {
        int n = bc + ty + i;
        float v = tile[tx][ty + i];
        if (n < scale_n) v *= qscale;
        out[(size_t)n * R + br + tx] = f2bf(v);
    }
}

// ---------------------------------------------------------------------------
// LayerNorm over rows of 1024, fp32 in -> bf16 out. One block (256) per row.
// ---------------------------------------------------------------------------
__global__ __launch_bounds__(256)
void ln_kernel(const float* __restrict__ x, const float* __restrict__ g,
               const float* __restrict__ b, ushort_t* __restrict__ out) {
    const int row = blockIdx.x;
    const int t = threadIdx.x;
    const float4 xv = ((const float4*)(x + (size_t)row * 1024))[t];
    float s  = xv.x + xv.y + xv.z + xv.w;
    float ss = xv.x*xv.x + xv.y*xv.y + xv.z*xv.z + xv.w*xv.w;
    #pragma unroll
    for (int off = 32; off > 0; off >>= 1) {
        s  += __shfl_xor(s, off);
        ss += __shfl_xor(ss, off);
    }
    __shared__ float red[8];
    int wave = t >> 6, lane = t & 63;
    if (lane == 0) { red[wave] = s; red[4 + wave] = ss; }
    __syncthreads();
    s  = red[0] + red[1] + red[2] + red[3];
    ss = red[4] + red[5] + red[6] + red[7];
    float mu  = s * (1.0f / 1024.0f);
    float var = ss * (1.0f / 1024.0f) - mu * mu;
    float rstd = rsqrtf(var + 1e-5f);
    float4 gv = ((const float4*)g)[t];
    float4 bv = ((const float4*)b)[t];
    ushort4 o;
    o.x = f2bf((xv.x - mu) * rstd * gv.x + bv.x);
    o.y = f2bf((xv.y - mu) * rstd * gv.y + bv.y);
    o.z = f2bf((xv.z - mu) * rstd * gv.z + bv.z);
    o.w = f2bf((xv.w - mu) * rstd * gv.w + bv.w);
    ((ushort4*)(out + (size_t)row * 1024))[t] = o;
}

// ---------------------------------------------------------------------------
// GEMM: C[M,N] = A[M,K] * Bt[N,K], bf16 in, fp32 acc. 128x128 tile, BK=64.
// XOR-swizzled LDS (chunk ^= row&7) applied at the GLOBAL source address.
// MODE 0: bf16 (n0>=2048 tiles go transposed to vTout when vTout != null:
//         vT[((b*16+h)*64+d)*2048 + t], packed 8B stores)
// MODE 1: f32 = acc+res | 2: bf16 = gelu(acc+bias) | 3: f32 = acc+bias+res
// ---------------------------------------------------------------------------
template<int MODE, int K, int N>
__global__ __launch_bounds__(256)
void gemm_bt(const ushort_t* __restrict__ A, const ushort_t* __restrict__ Bt,
             void* __restrict__ Cout, const float* __restrict__ bias,
             const float* __restrict__ res, ushort_t* __restrict__ vTout) {
    constexpr int BK = 64;
    __shared__ __align__(16) ushort_t As[128 * 64];
    __shared__ __align__(16) ushort_t Bs[128 * 64];
    const int tid = threadIdx.x;
    const int wave = tid >> 6, lane = tid & 63;
    const int quad = lane >> 4, l16 = lane & 15;
    const int m0 = blockIdx.y * 128, n0 = blockIdx.x * 128;
    const int wm = (wave >> 1) * 64, wn = (wave & 1) * 64;

    const int r0 = tid >> 3, pc = tid & 7;
    const int lc = pc ^ (r0 & 7);
    const ushort_t* aSrc = A  + (size_t)(m0 + r0) * K + lc * 8;
    const ushort_t* bSrc = Bt + (size_t)(n0 + r0) * K + lc * 8;
    char* aDst = (char*)As + wave * 1024;
    char* bDst = (char*)Bs + wave * 1024;
    const int swz = l16 & 7;

    f32x4 acc[4][4] = {};

    for (int k0 = 0; k0 < K; k0 += BK) {
        __syncthreads();
        #pragma unroll
        for (int c = 0; c < 4; ++c) {
            gl2lds(aSrc + (size_t)c * 32 * K + k0, aDst + c * 4096);
            gl2lds(bSrc + (size_t)c * 32 * K + k0, bDst + c * 4096);
        }
        __syncthreads();
        #pragma unroll
        for (int ks = 0; ks < 2; ++ks) {
            const int cko = ((ks * 4 + quad) ^ swz) * 8;
            bf16x8 af[4], bfr[4];
            #pragma unroll
            for (int i = 0; i < 4; ++i)
                af[i] = *(const bf16x8*)(&As[(wm + i * 16 + l16) * 64 + cko]);
            #pragma unroll
            for (int j = 0; j < 4; ++j)
                bfr[j] = *(const bf16x8*)(&Bs[(wn + j * 16 + l16) * 64 + cko]);
            #pragma unroll
            for (int i = 0; i < 4; ++i)
                #pragma unroll
                for (int j = 0; j < 4; ++j)
                    acc[i][j] = __builtin_amdgcn_mfma_f32_16x16x32_bf16(
                        af[i], bfr[j], acc[i][j], 0, 0, 0);
        }
    }

    // epilogue: C/D layout col = lane&15, row = quad*4 + reg
    if constexpr (MODE == 0) {
        if (vTout && n0 >= 2048) {
            // V tile: write transposed, 4 consecutive t per lane as one 8B store
            #pragma unroll
            for (int i = 0; i < 4; ++i) {
                int m = m0 + wm + i * 16 + quad * 4;
                int bb = m >> 11, t = m & 2047;
                #pragma unroll
                for (int j = 0; j < 4; ++j) {
                    int nn = n0 - 2048 + wn + j * 16 + l16;
                    int h = nn >> 6, d = nn & 63;
                    uint2 pk;
                    pk.x = pack2bf(acc[i][j][0], acc[i][j][1]);
                    pk.y = pack2bf(acc[i][j][2], acc[i][j][3]);
                    *(uint2*)(vTout + ((size_t)(bb * 16 + h) * 64 + d) * 2048 + t) = pk;
                }
            }
            return;
        }
    }
    float bj[4];
    if constexpr (MODE == 2 || MODE == 3) {
        #pragma unroll
        for (int j = 0; j < 4; ++j) bj[j] = bias[n0 + wn + j * 16 + l16];
    }
    #pragma unroll
    for (int i = 0; i < 4; ++i) {
        #pragma unroll
        for (int j = 0; j < 4; ++j) {
            #pragma unroll
            for (int r = 0; r < 4; ++r) {
                int m = m0 + wm + i * 16 + quad * 4 + r;
                int n = n0 + wn + j * 16 + l16;
                size_t idx = (size_t)m * N + n;
                float v = acc[i][j][r];
                if constexpr (MODE == 0) {
                    ((ushort_t*)Cout)[idx] = f2bf(v);
                } else if constexpr (MODE == 1) {
                    ((float*)Cout)[idx] = v + res[idx];
                } else if constexpr (MODE == 2) {
                    ((ushort_t*)Cout)[idx] = f2bf(fast_gelu(v + bj[j]));
                } else {
                    ((float*)Cout)[idx] = v + bj[j] + res[idx];
                }
            }
        }
    }
}

// ---------------------------------------------------------------------------
// Flash attention, S^T formulation, no max-subtraction, double-buffered K/V.
// qkv bf16 [4,2048,3072] (Q pre-scaled by 0.125*log2e), vT [64bh][64d][2048t].
// Block = (q-tile 128, bh); 4 waves x 32 q rows. One barrier per KV tile.
// ---------------------------------------------------------------------------
__global__ __launch_bounds__(256)
void attn_kernel(const ushort_t* __restrict__ qkv, const ushort_t* __restrict__ vT,
                 ushort_t* __restrict__ out) {
    constexpr int T = 2048, C3 = 3072, BQ = 128;
    __shared__ __align__(16) ushort_t Ks[2][64 * 64];   // [key][d], swizzled
    __shared__ __align__(16) ushort_t Vs[2][64 * 64];   // [d][key], swizzled
    __shared__ __align__(16) ushort_t Ps[BQ * 64];      // [q][key], swizzled chunks
    const int bh = blockIdx.y, b = bh >> 4, h = bh & 15;
    const int qt = blockIdx.x;
    const int tid = threadIdx.x, wave = tid >> 6, lane = tid & 63;
    const int quad = lane >> 4, l16 = lane & 15;
    const int swz = l16 & 7;

    // Q B-frags in registers: lane l16 = q, i = q-block, ks = d-half
    bf16x8 qf[2][2];
    {
        const ushort_t* Qg = qkv + ((size_t)b * T + qt * BQ + wave * 32) * C3 + h * 64;
        #pragma unroll
        for (int i = 0; i < 2; ++i)
            #pragma unroll
            for (int ks = 0; ks < 2; ++ks)
                qf[i][ks] = *(const bf16x8*)(Qg + (size_t)(i * 16 + l16) * C3 + ks * 32 + quad * 8);
    }
    // staging sources (swizzled chunks)
    const int r0 = tid >> 3, pc = tid & 7;
    const int lc = pc ^ (r0 & 7);
    const ushort_t* KgB = qkv + (size_t)b * T * C3 + 1024 + h * 64 + (size_t)r0 * C3 + lc * 8;
    const ushort_t* VgB = vT + (size_t)bh * 64 * T + (size_t)r0 * T + lc * 8;
    char* kDst0 = (char*)&Ks[0][0] + wave * 1024;
    char* vDst0 = (char*)&Vs[0][0] + wave * 1024;

    f32x4 o_acc[2][4] = {};
    float l_part[2] = {0.0f, 0.0f};
    const int prow = (wave * 32 + l16) * 64;

    // prologue: stage tile 0 into buffer 0
    #pragma unroll
    for (int c = 0; c < 2; ++c) {
        gl2lds(KgB + (size_t)c * 32 * C3, kDst0 + c * 4096);
        gl2lds(VgB + (size_t)c * 32 * T,  vDst0 + c * 4096);
    }

    for (int kt = 0; kt < T / 64; ++kt) {
        const int cur = kt & 1;
        __syncthreads();   // buf[cur] staged; buf[cur^1] readers (2 iters back) done
        if (kt + 1 < T / 64) {
            const int nb = (cur ^ 1) * 8192;
            #pragma unroll
            for (int c = 0; c < 2; ++c) {
                gl2lds(KgB + ((size_t)(kt + 1) * 64 + c * 32) * C3, kDst0 + nb + c * 4096);
                gl2lds(VgB + (size_t)c * 32 * T + (kt + 1) * 64,    vDst0 + nb + c * 4096);
            }
        }
        const ushort_t* Kc = &Ks[cur][0];
        const ushort_t* Vc = &Vs[cur][0];

        // S^T = K * Q^T : D col = q = l16, row = key = j*16 + quad*4 + r
        f32x4 s[2][4] = {};
        #pragma unroll
        for (int ks = 0; ks < 2; ++ks) {
            const int cko = ((ks * 4 + quad) ^ swz) * 8;
            bf16x8 kf[4];
            #pragma unroll
            for (int j = 0; j < 4; ++j)
                kf[j] = *(const bf16x8*)(&Kc[(j * 16 + l16) * 64 + cko]);
            #pragma unroll
            for (int i = 0; i < 2; ++i)
                #pragma unroll
                for (int j = 0; j < 4; ++j)
                    s[i][j] = __builtin_amdgcn_mfma_f32_16x16x32_bf16(
                        kf[j], qf[i][ks], s[i][j], 0, 0, 0);
        }

        // p = 2^s, accumulate l, pack to bf16 P (swizzled chunk write)
        #pragma unroll
        for (int i = 0; i < 2; ++i) {
            #pragma unroll
            for (int j = 0; j < 4; ++j) {
                float p0 = __builtin_amdgcn_exp2f(s[i][j][0]);
                float p1 = __builtin_amdgcn_exp2f(s[i][j][1]);
                float p2 = __builtin_amdgcn_exp2f(s[i][j][2]);
                float p3 = __builtin_amdgcn_exp2f(s[i][j][3]);
                l_part[i] += (p0 + p1) + (p2 + p3);
                uint2 pk;
                pk.x = pack2bf(p0, p1);
                pk.y = pack2bf(p2, p3);
                const int c2 = (j * 2 + (quad >> 1)) ^ swz;
                *(uint2*)(&Ps[prow + i * 16 * 64 + c2 * 8 + (quad & 1) * 4]) = pk;
            }
        }

        // O += P V : A = P[q][key] (own wave rows), B = Vs[d][key]
        #pragma unroll
        for (int ks2 = 0; ks2 < 2; ++ks2) {
            const int cko = ((ks2 * 4 + quad) ^ swz) * 8;
            bf16x8 pf[2], vf[4];
            #pragma unroll
            for (int i = 0; i < 2; ++i)
                pf[i] = *(const bf16x8*)(&Ps[prow + i * 16 * 64 + cko]);
            #pragma unroll
            for (int j = 0; j < 4; ++j)
                vf[j] = *(const bf16x8*)(&Vc[(j * 16 + l16) * 64 + cko]);
            #pragma unroll
            for (int i = 0; i < 2; ++i)
                #pragma unroll
                for (int j = 0; j < 4; ++j)
                    o_acc[i][j] = __builtin_amdgcn_mfma_f32_16x16x32_bf16(
                        pf[i], vf[j], o_acc[i][j], 0, 0, 0);
        }
    }

    // reduce l across quads (lanes sharing l16), broadcast, normalize, store
    #pragma unroll
    for (int i = 0; i < 2; ++i) {
        float lt = l_part[i];
        lt += __shfl_xor(lt, 16);
        lt += __shfl_xor(lt, 32);
        #pragma unroll
        for (int r = 0; r < 4; ++r) {
            float lv = __shfl(lt, quad * 4 + r);
            float inv = 1.0f / lv;
            int row = qt * BQ + wave * 32 + i * 16 + quad * 4 + r;
            size_t orow = ((size_t)b * T + row) * 1024 + h * 64;
            #pragma unroll
            for (int j = 0; j < 4; ++j)
                out[orow + j * 16 + l16] = f2bf(o_acc[i][j][r] * inv);
        }
    }
}

// ---------------------------------------------------------------------------
extern "C" void kernel_launch(void* const* d_in, const int* in_sizes, int n_in,
                              void* d_out, int out_size, void* d_ws, size_t ws_size,
                              hipStream_t stream) {
    const float* x     = (const float*)d_in[0];
    const float* ln1g  = (const float*)d_in[1];
    const float* ln1b  = (const float*)d_in[2];
    const float* ln2g  = (const float*)d_in[3];
    const float* ln2b  = (const float*)d_in[4];
    const float* wqkv  = (const float*)d_in[5];
    const float* wproj = (const float*)d_in[6];
    const float* w1    = (const float*)d_in[7];
    const float* b1    = (const float*)d_in[8];
    const float* w2    = (const float*)d_in[9];
    const float* b2    = (const float*)d_in[10];
    float* out = (float*)d_out;

    const size_t MT = 8192;  // B*T
    ushort_t* wqkvT  = (ushort_t*)d_ws;              // [3072][1024]
    ushort_t* wprojT = wqkvT  + (size_t)3072 * 1024; // [1024][1024]
    ushort_t* w1T    = wprojT + (size_t)1024 * 1024; // [4096][1024]
    ushort_t* w2T    = w1T    + (size_t)4096 * 1024; // [1024][4096]
    ushort_t* xn     = w2T    + (size_t)1024 * 4096; // [8192][1024] bf16
    ushort_t* qkvb   = xn     + MT * 1024;           // [8192][3072] bf16 (V part unused)
    ushort_t* attnb  = qkvb   + MT * 3072;           // [8192][1024] bf16
    float*    x2     = (float*)(attnb + MT * 1024);  // [8192][1024] f32
    ushort_t* xn2    = (ushort_t*)(x2 + MT * 1024);  // [8192][1024] bf16
    ushort_t* h1     = xn;                 // reuse xn+qkvb (both dead): [8192][4096]
    ushort_t* vT     = (ushort_t*)x2;      // reuse x2 region pre-proj: [64][64][2048]

    dim3 blk256(256);
    dim3 tblk(32, 8);
    const float qscale = 0.125f * 1.4426950408889634f;  // score scale * log2(e), folded into Q

    tcast_all<<<dim3(12288), tblk, 0, stream>>>(wqkv, wproj, w1, w2,
                                                wqkvT, wprojT, w1T, w2T, qscale);

    ln_kernel<<<dim3(8192), blk256, 0, stream>>>(x, ln1g, ln1b, xn);
    gemm_bt<0, 1024, 3072><<<dim3(24, 64), blk256, 0, stream>>>(xn, wqkvT, qkvb, nullptr, nullptr, vT);
    attn_kernel<<<dim3(16, 64), blk256, 0, stream>>>(qkvb, vT, attnb);
    gemm_bt<1, 1024, 1024><<<dim3(8, 64), blk256, 0, stream>>>(attnb, wprojT, x2, nullptr, x, nullptr);
    ln_kernel<<<dim3(8192), blk256, 0, stream>>>(x2, ln2g, ln2b, xn2);
    gemm_bt<2, 1024, 4096><<<dim3(32, 64), blk256, 0, stream>>>(xn2, w1T, h1, b1, nullptr, nullptr);
    gemm_bt<3, 4096, 1024><<<dim3(8, 64), blk256, 0, stream>>>(h1, w2T, out, b2, x2, nullptr);
}

// Round 5
// 499.318 us; speedup vs baseline: 1.0126x; 1.0126x over previous
//
#include <hip/hip_runtime.h>
#include <hip/hip_bf16.h>
#include <math.h>

typedef __attribute__((ext_vector_type(8))) short bf16x8;   // 8 bf16 in 4 VGPRs
typedef __attribute__((ext_vector_type(4))) float f32x4;    // MFMA C/D frag
typedef unsigned short ushort_t;

__device__ __forceinline__ ushort_t f2bf(float f) {
    union { float f; unsigned u; } v; v.f = f;
    unsigned r = v.u + 0x7FFF + ((v.u >> 16) & 1);   // RNE
    return (ushort_t)(r >> 16);
}

// pack two f32 -> 2 bf16 (round-half-up): 2 adds + 1 v_perm; a in low half
__device__ __forceinline__ unsigned pack2bf(float a, float b) {
    union { float f; unsigned u; } x, y; x.f = a; y.f = b;
    return __builtin_amdgcn_perm(y.u + 0x8000u, x.u + 0x8000u, 0x07060302u);
}

// async 16B global -> LDS (wave-uniform LDS base; lane data lands at base+lane*16)
__device__ __forceinline__ void gl2lds(const void* g, void* l) {
    __builtin_amdgcn_global_load_lds(
        (const __attribute__((address_space(1))) void*)g,
        (__attribute__((address_space(3))) void*)l, 16, 0, 0);
}

// fast GELU (tanh form via sigmoid): max |err| vs erf-GELU ~1e-3
__device__ __forceinline__ float fast_gelu(float tt) {
    float t2 = tt * tt;
    float arg = tt * fmaf(0.07135481283f, t2, 1.595769122f);
    float e = __builtin_amdgcn_exp2f(arg * -1.442695041f);
    return tt * __builtin_amdgcn_rcpf(1.0f + e);
}

// ---------------------------------------------------------------------------
// Merged transpose+cast for all 4 weights (one launch).
// ---------------------------------------------------------------------------
__global__ __launch_bounds__(256)
void tcast_all(const float* __restrict__ wqkv, const float* __restrict__ wproj,
               const float* __restrict__ w1, const float* __restrict__ w2,
               ushort_t* __restrict__ wqkvT, ushort_t* __restrict__ wprojT,
               ushort_t* __restrict__ w1T, ushort_t* __restrict__ w2T,
               float qscale) {
    __shared__ float tile[32][33];
    int id = blockIdx.x;
    const float* in; ushort_t* out; int R, Cc, gx, scale_n;
    if (id < 3072)      { in = wqkv;  out = wqkvT;  R = 1024; Cc = 3072; gx = 96;  scale_n = 1024; }
    else if (id < 4096) { id -= 3072; in = wproj; out = wprojT; R = 1024; Cc = 1024; gx = 32; scale_n = 0; }
    else if (id < 8192) { id -= 4096; in = w1;    out = w1T;    R = 1024; Cc = 4096; gx = 128; scale_n = 0; }
    else                { id -= 8192; in = w2;    out = w2T;    R = 4096; Cc = 1024; gx = 32; scale_n = 0; }
    int bc = (id % gx) * 32, br = (id / gx) * 32;
    int tx = threadIdx.x, ty = threadIdx.y;
    #pragma unroll
    for (int i = 0; i < 32; i += 8)
        tile[ty + i][tx] = in[(size_t)(br + ty + i) * Cc + bc + tx];
    __syncthreads();
    #pragma unroll
    for (int i = 0; i < 32; i += 8) {
        int n = bc + ty + i;
        float v = tile[tx][ty + i];
        if (n < scale_n) v *= qscale;
        out[(size_t)n * R + br + tx] = f2bf(v);
    }
}

// ---------------------------------------------------------------------------
// LayerNorm over rows of 1024, fp32 in -> bf16 out. One block (256) per row.
// ---------------------------------------------------------------------------
__global__ __launch_bounds__(256)
void ln_kernel(const float* __restrict__ x, const float* __restrict__ g,
               const float* __restrict__ b, ushort_t* __restrict__ out) {
    const int row = blockIdx.x;
    const int t = threadIdx.x;
    const float4 xv = ((const float4*)(x + (size_t)row * 1024))[t];
    float s  = xv.x + xv.y + xv.z + xv.w;
    float ss = xv.x*xv.x + xv.y*xv.y + xv.z*xv.z + xv.w*xv.w;
    #pragma unroll
    for (int off = 32; off > 0; off >>= 1) {
        s  += __shfl_xor(s, off);
        ss += __shfl_xor(ss, off);
    }
    __shared__ float red[8];
    int wave = t >> 6, lane = t & 63;
    if (lane == 0) { red[wave] = s; red[4 + wave] = ss; }
    __syncthreads();
    s  = red[0] + red[1] + red[2] + red[3];
    ss = red[4] + red[5] + red[6] + red[7];
    float mu  = s * (1.0f / 1024.0f);
    float var = ss * (1.0f / 1024.0f) - mu * mu;
    float rstd = rsqrtf(var + 1e-5f);
    float4 gv = ((const float4*)g)[t];
    float4 bv = ((const float4*)b)[t];
    ushort4 o;
    o.x = f2bf((xv.x - mu) * rstd * gv.x + bv.x);
    o.y = f2bf((xv.y - mu) * rstd * gv.y + bv.y);
    o.z = f2bf((xv.z - mu) * rstd * gv.z + bv.z);
    o.w = f2bf((xv.w - mu) * rstd * gv.w + bv.w);
    ((ushort4*)(out + (size_t)row * 1024))[t] = o;
}

// ---------------------------------------------------------------------------
// GEMM: C[M,N] = A[M,K] * Bt[N,K], bf16 in, fp32 acc. 128x128 tile, BK=64.
// XOR-swizzled LDS (chunk ^= row&7) applied at the GLOBAL source address.
// MODE 0: bf16 (n0>=2048 tiles transposed to vTout when non-null)
// MODE 1: f32 = acc+res | 2: bf16 = gelu(acc+bias) | 3: f32 = acc+bias+res
// ---------------------------------------------------------------------------
template<int MODE, int K, int N>
__global__ __launch_bounds__(256)
void gemm_bt(const ushort_t* __restrict__ A, const ushort_t* __restrict__ Bt,
             void* __restrict__ Cout, const float* __restrict__ bias,
             const float* __restrict__ res, ushort_t* __restrict__ vTout) {
    constexpr int BK = 64;
    __shared__ __align__(16) ushort_t As[128 * 64];
    __shared__ __align__(16) ushort_t Bs[128 * 64];
    const int tid = threadIdx.x;
    const int wave = tid >> 6, lane = tid & 63;
    const int quad = lane >> 4, l16 = lane & 15;
    const int m0 = blockIdx.y * 128, n0 = blockIdx.x * 128;
    const int wm = (wave >> 1) * 64, wn = (wave & 1) * 64;

    const int r0 = tid >> 3, pc = tid & 7;
    const int lc = pc ^ (r0 & 7);
    const ushort_t* aSrc = A  + (size_t)(m0 + r0) * K + lc * 8;
    const ushort_t* bSrc = Bt + (size_t)(n0 + r0) * K + lc * 8;
    char* aDst = (char*)As + wave * 1024;
    char* bDst = (char*)Bs + wave * 1024;
    const int swz = l16 & 7;

    f32x4 acc[4][4] = {};

    for (int k0 = 0; k0 < K; k0 += BK) {
        __syncthreads();
        #pragma unroll
        for (int c = 0; c < 4; ++c) {
            gl2lds(aSrc + (size_t)c * 32 * K + k0, aDst + c * 4096);
            gl2lds(bSrc + (size_t)c * 32 * K + k0, bDst + c * 4096);
        }
        __syncthreads();
        #pragma unroll
        for (int ks = 0; ks < 2; ++ks) {
            const int cko = ((ks * 4 + quad) ^ swz) * 8;
            bf16x8 af[4], bfr[4];
            #pragma unroll
            for (int i = 0; i < 4; ++i)
                af[i] = *(const bf16x8*)(&As[(wm + i * 16 + l16) * 64 + cko]);
            #pragma unroll
            for (int j = 0; j < 4; ++j)
                bfr[j] = *(const bf16x8*)(&Bs[(wn + j * 16 + l16) * 64 + cko]);
            #pragma unroll
            for (int i = 0; i < 4; ++i)
                #pragma unroll
                for (int j = 0; j < 4; ++j)
                    acc[i][j] = __builtin_amdgcn_mfma_f32_16x16x32_bf16(
                        af[i], bfr[j], acc[i][j], 0, 0, 0);
        }
    }

    // epilogue: C/D layout col = lane&15, row = quad*4 + reg
    if constexpr (MODE == 0) {
        if (vTout && n0 >= 2048) {
            #pragma unroll
            for (int i = 0; i < 4; ++i) {
                int m = m0 + wm + i * 16 + quad * 4;
                int bb = m >> 11, t = m & 2047;
                #pragma unroll
                for (int j = 0; j < 4; ++j) {
                    int nn = n0 - 2048 + wn + j * 16 + l16;
                    int h = nn >> 6, d = nn & 63;
                    uint2 pk;
                    pk.x = pack2bf(acc[i][j][0], acc[i][j][1]);
                    pk.y = pack2bf(acc[i][j][2], acc[i][j][3]);
                    *(uint2*)(vTout + ((size_t)(bb * 16 + h) * 64 + d) * 2048 + t) = pk;
                }
            }
            return;
        }
    }
    float bj[4];
    if constexpr (MODE == 2 || MODE == 3) {
        #pragma unroll
        for (int j = 0; j < 4; ++j) bj[j] = bias[n0 + wn + j * 16 + l16];
    }
    #pragma unroll
    for (int i = 0; i < 4; ++i) {
        #pragma unroll
        for (int j = 0; j < 4; ++j) {
            #pragma unroll
            for (int r = 0; r < 4; ++r) {
                int m = m0 + wm + i * 16 + quad * 4 + r;
                int n = n0 + wn + j * 16 + l16;
                size_t idx = (size_t)m * N + n;
                float v = acc[i][j][r];
                if constexpr (MODE == 0) {
                    ((ushort_t*)Cout)[idx] = f2bf(v);
                } else if constexpr (MODE == 1) {
                    ((float*)Cout)[idx] = v + res[idx];
                } else if constexpr (MODE == 2) {
                    ((ushort_t*)Cout)[idx] = f2bf(fast_gelu(v + bj[j]));
                } else {
                    ((float*)Cout)[idx] = v + bj[j] + res[idx];
                }
            }
        }
    }
}

// ---------------------------------------------------------------------------
// Flash attention, S^T formulation, no max-subtraction, double-buffered K/V,
// in-register P transpose via v_permlane{32,16}_swap_b32 (no P LDS round-trip).
// qkv bf16 [4,2048,3072] (Q pre-scaled by 0.125*log2e), vT [64bh][64d][2048t].
// grid (bh, qt): 16 q-tile blocks of one head share an XCD (id%8 round-robin).
// ---------------------------------------------------------------------------
__global__ __launch_bounds__(256)
void attn_kernel(const ushort_t* __restrict__ qkv, const ushort_t* __restrict__ vT,
                 ushort_t* __restrict__ out) {
    constexpr int T = 2048, C3 = 3072, BQ = 128;
    __shared__ __align__(16) ushort_t Ks[2][64 * 64];   // [key][d], swizzled
    __shared__ __align__(16) ushort_t Vs[2][64 * 64];   // [d][key], swizzled
    const int bh = blockIdx.x, b = bh >> 4, h = bh & 15;
    const int qt = blockIdx.y;
    const int tid = threadIdx.x, wave = tid >> 6, lane = tid & 63;
    const int quad = lane >> 4, l16 = lane & 15;
    const int swz = l16 & 7;

    // Q B-frags in registers: lane l16 = q, i = q-block, ks = d-half
    bf16x8 qf[2][2];
    {
        const ushort_t* Qg = qkv + ((size_t)b * T + qt * BQ + wave * 32) * C3 + h * 64;
        #pragma unroll
        for (int i = 0; i < 2; ++i)
            #pragma unroll
            for (int ks = 0; ks < 2; ++ks)
                qf[i][ks] = *(const bf16x8*)(Qg + (size_t)(i * 16 + l16) * C3 + ks * 32 + quad * 8);
    }
    // staging sources (swizzled chunks)
    const int r0 = tid >> 3, pc = tid & 7;
    const int lc = pc ^ (r0 & 7);
    const ushort_t* KgB = qkv + (size_t)b * T * C3 + 1024 + h * 64 + (size_t)r0 * C3 + lc * 8;
    const ushort_t* VgB = vT + (size_t)bh * 64 * T + (size_t)r0 * T + lc * 8;
    char* kDst0 = (char*)&Ks[0][0] + wave * 1024;
    char* vDst0 = (char*)&Vs[0][0] + wave * 1024;

    f32x4 o_acc[2][4] = {};
    float l_part[2] = {0.0f, 0.0f};

    // prologue: stage tile 0 into buffer 0
    #pragma unroll
    for (int c = 0; c < 2; ++c) {
        gl2lds(KgB + (size_t)c * 32 * C3, kDst0 + c * 4096);
        gl2lds(VgB + (size_t)c * 32 * T,  vDst0 + c * 4096);
    }

    for (int kt = 0; kt < T / 64; ++kt) {
        const int cur = kt & 1;
        __syncthreads();   // buf[cur] staged; buf[cur^1] readers (prev iter) done
        if (kt + 1 < T / 64) {
            const int nb = (cur ^ 1) * 8192;
            #pragma unroll
            for (int c = 0; c < 2; ++c) {
                gl2lds(KgB + ((size_t)(kt + 1) * 64 + c * 32) * C3, kDst0 + nb + c * 4096);
                gl2lds(VgB + (size_t)c * 32 * T + (kt + 1) * 64,    vDst0 + nb + c * 4096);
            }
        }
        const ushort_t* Kc = &Ks[cur][0];
        const ushort_t* Vc = &Vs[cur][0];

        // S^T = K * Q^T : D col = q = l16, row = key = j*16 + quad*4 + r
        f32x4 s[2][4] = {};
        #pragma unroll
        for (int ks = 0; ks < 2; ++ks) {
            const int cko = ((ks * 4 + quad) ^ swz) * 8;
            bf16x8 kf[4];
            #pragma unroll
            for (int j = 0; j < 4; ++j)
                kf[j] = *(const bf16x8*)(&Kc[(j * 16 + l16) * 64 + cko]);
            #pragma unroll
            for (int i = 0; i < 2; ++i)
                #pragma unroll
                for (int j = 0; j < 4; ++j)
                    s[i][j] = __builtin_amdgcn_mfma_f32_16x16x32_bf16(
                        kf[j], qf[i][ks], s[i][j], 0, 0, 0);
        }

        // p = 2^s, accumulate l, pack, transpose C-frag -> A-frag in registers.
        // Source (lane quad sq): u[j][h] = keys (j*16+sq*4+2h, +1) of q=l16(+16i).
        // Dest A-frag ks2, lane quad q, dword e2 = keys (ks2*32+q*8+2*e2, +1).
        // (A,B)=(u[2ks2][h], u[2ks2+1][h]) --permlane32_swap,permlane16_swap-->
        //   A=[A.q0,A.q2,B.q0,B.q2]=dword(h), B=[A.q1,A.q3,B.q1,B.q3]=dword(2+h).
        bf16x8 pf[2][2];
        #pragma unroll
        for (int i = 0; i < 2; ++i) {
            unsigned u[4][2];
            #pragma unroll
            for (int j = 0; j < 4; ++j) {
                float p0 = __builtin_amdgcn_exp2f(s[i][j][0]);
                float p1 = __builtin_amdgcn_exp2f(s[i][j][1]);
                float p2 = __builtin_amdgcn_exp2f(s[i][j][2]);
                float p3 = __builtin_amdgcn_exp2f(s[i][j][3]);
                l_part[i] += (p0 + p1) + (p2 + p3);
                u[j][0] = pack2bf(p0, p1);
                u[j][1] = pack2bf(p2, p3);
            }
            #pragma unroll
            for (int ks2 = 0; ks2 < 2; ++ks2) {
                unsigned d0 = u[2 * ks2][0], d2 = u[2 * ks2 + 1][0];
                asm("v_permlane32_swap_b32 %0, %1\n\t"
                    "v_permlane16_swap_b32 %0, %1" : "+v"(d0), "+v"(d2));
                unsigned d1 = u[2 * ks2][1], d3 = u[2 * ks2 + 1][1];
                asm("v_permlane32_swap_b32 %0, %1\n\t"
                    "v_permlane16_swap_b32 %0, %1" : "+v"(d1), "+v"(d3));
                union { unsigned d[4]; bf16x8 v; } fr;
                fr.d[0] = d0; fr.d[1] = d1; fr.d[2] = d2; fr.d[3] = d3;
                pf[i][ks2] = fr.v;
            }
        }

        // O += P V : A = pf (registers), B = Vs[d][key]
        #pragma unroll
        for (int ks2 = 0; ks2 < 2; ++ks2) {
            const int cko = ((ks2 * 4 + quad) ^ swz) * 8;
            bf16x8 vf[4];
            #pragma unroll
            for (int j = 0; j < 4; ++j)
                vf[j] = *(const bf16x8*)(&Vc[(j * 16 + l16) * 64 + cko]);
            #pragma unroll
            for (int i = 0; i < 2; ++i)
                #pragma unroll
                for (int j = 0; j < 4; ++j)
                    o_acc[i][j] = __builtin_amdgcn_mfma_f32_16x16x32_bf16(
                        pf[i][ks2], vf[j], o_acc[i][j], 0, 0, 0);
        }
    }

    // reduce l across quads (lanes sharing l16), broadcast, normalize, store
    #pragma unroll
    for (int i = 0; i < 2; ++i) {
        float lt = l_part[i];
        lt += __shfl_xor(lt, 16);
        lt += __shfl_xor(lt, 32);
        #pragma unroll
        for (int r = 0; r < 4; ++r) {
            float lv = __shfl(lt, quad * 4 + r);
            float inv = 1.0f / lv;
            int row = qt * BQ + wave * 32 + i * 16 + quad * 4 + r;
            size_t orow = ((size_t)b * T + row) * 1024 + h * 64;
            #pragma unroll
            for (int j = 0; j < 4; ++j)
                out[orow + j * 16 + l16] = f2bf(o_acc[i][j][r] * inv);
        }
    }
}

// ---------------------------------------------------------------------------
extern "C" void kernel_launch(void* const* d_in, const int* in_sizes, int n_in,
                              void* d_out, int out_size, void* d_ws, size_t ws_size,
                              hipStream_t stream) {
    const float* x     = (const float*)d_in[0];
    const float* ln1g  = (const float*)d_in[1];
    const float* ln1b  = (const float*)d_in[2];
    const float* ln2g  = (const float*)d_in[3];
    const float* ln2b  = (const float*)d_in[4];
    const float* wqkv  = (const float*)d_in[5];
    const float* wproj = (const float*)d_in[6];
    const float* w1    = (const float*)d_in[7];
    const float* b1    = (const float*)d_in[8];
    const float* w2    = (const float*)d_in[9];
    const float* b2    = (const float*)d_in[10];
    float* out = (float*)d_out;

    const size_t MT = 8192;  // B*T
    ushort_t* wqkvT  = (ushort_t*)d_ws;              // [3072][1024]
    ushort_t* wprojT = wqkvT  + (size_t)3072 * 1024; // [1024][1024]
    ushort_t* w1T    = wprojT + (size_t)1024 * 1024; // [4096][1024]
    ushort_t* w2T    = w1T    + (size_t)4096 * 1024; // [1024][4096]
    ushort_t* xn     = w2T    + (size_t)1024 * 4096; // [8192][1024] bf16
    ushort_t* qkvb   = xn     + MT * 1024;           // [8192][3072] bf16 (V part unused)
    ushort_t* attnb  = qkvb   + MT * 3072;           // [8192][1024] bf16
    float*    x2     = (float*)(attnb + MT * 1024);  // [8192][1024] f32
    ushort_t* xn2    = (ushort_t*)(x2 + MT * 1024);  // [8192][1024] bf16
    ushort_t* h1     = xn;                 // reuse xn+qkvb (both dead): [8192][4096]
    ushort_t* vT     = (ushort_t*)x2;      // reuse x2 region pre-proj: [64][64][2048]

    dim3 blk256(256);
    dim3 tblk(32, 8);
    const float qscale = 0.125f * 1.4426950408889634f;  // score scale * log2(e), folded into Q

    tcast_all<<<dim3(12288), tblk, 0, stream>>>(wqkv, wproj, w1, w2,
                                                wqkvT, wprojT, w1T, w2T, qscale);

    ln_kernel<<<dim3(8192), blk256, 0, stream>>>(x, ln1g, ln1b, xn);
    gemm_bt<0, 1024, 3072><<<dim3(24, 64), blk256, 0, stream>>>(xn, wqkvT, qkvb, nullptr, nullptr, vT);
    attn_kernel<<<dim3(64, 16), blk256, 0, stream>>>(qkvb, vT, attnb);
    gemm_bt<1, 1024, 1024><<<dim3(8, 64), blk256, 0, stream>>>(attnb, wprojT, x2, nullptr, x, nullptr);
    ln_kernel<<<dim3(8192), blk256, 0, stream>>>(x2, ln2g, ln2b, xn2);
    gemm_bt<2, 1024, 4096><<<dim3(32, 64), blk256, 0, stream>>>(xn2, w1T, h1, b1, nullptr, nullptr);
    gemm_bt<3, 4096, 1024><<<dim3(8, 64), blk256, 0, stream>>>(h1, w2T, out, b2, x2, nullptr);
}